// Round 1
// baseline (55746.967 us; speedup 1.0000x reference)
//
#include <hip/hip_runtime.h>
#include <hip/hip_bf16.h>
#include <cstdint>
#include <cstddef>

#define N_NODES 100000
#define N_EDGES 1600000

typedef __attribute__((ext_vector_type(8))) short short8;
typedef __attribute__((ext_vector_type(4))) float floatx4;

__device__ inline float bf_lo(unsigned int u) { return __uint_as_float(u << 16); }
__device__ inline float bf_hi(unsigned int u) { return __uint_as_float(u & 0xffff0000u); }
__device__ inline unsigned short f2bf(float f) {
  unsigned int u = __float_as_uint(f);
  u += 0x7fffu + ((u >> 16) & 1u);   // round-nearest-even
  return (unsigned short)(u >> 16);
}

// ---------- fp32 -> bf16 conversion, 4 elems/thread ----------
__global__ void cvt_f32_bf16(const float* __restrict__ in,
                             unsigned short* __restrict__ out, int n4) {
  int t = blockIdx.x * blockDim.x + threadIdx.x;
  if (t >= n4) return;
  float4 v = ((const float4*)in)[t];
  ushort4 o;
  o.x = f2bf(v.x); o.y = f2bf(v.y); o.z = f2bf(v.z); o.w = f2bf(v.w);
  ((ushort4*)out)[t] = o;
}

// ---------- degree ----------
__global__ void degree_kernel(const int* __restrict__ dst, float* __restrict__ deg) {
  int e = blockIdx.x * blockDim.x + threadIdx.x;
  if (e < N_EDGES) atomicAdd(deg + dst[e], 1.0f);
}
__global__ void inv_kernel(float* __restrict__ deg) {
  int n = blockIdx.x * blockDim.x + threadIdx.x;
  if (n < N_NODES) deg[n] = 1.0f / fmaxf(deg[n], 1.0f);
}

// ---------- scatter-add: S[dst] += h[src] (bf16 in, fp32 accum) ----------
// SPLIT threads per edge, each handles D/SPLIT contiguous feats in 8-wide chunks.
template<int D, int SPLIT>
__global__ void scatter_kernel(const unsigned short* __restrict__ h,
                               const int* __restrict__ src,
                               const int* __restrict__ dst,
                               float* __restrict__ S) {
  int t = blockIdx.x * blockDim.x + threadIdx.x;
  int e = t / SPLIT;
  int part = t % SPLIT;
  if (e >= N_EDGES) return;
  int sn = src[e], dn = dst[e];
  const int SEG = D / SPLIT;           // feats per thread
  const uint4* hrow = (const uint4*)(h + (size_t)sn * D + part * SEG);
  float* srow = S + (size_t)dn * D + part * SEG;
#pragma unroll
  for (int c = 0; c < SEG / 8; ++c) {
    uint4 p = hrow[c];
    float* q = srow + c * 8;
    atomicAdd(q + 0, bf_lo(p.x)); atomicAdd(q + 1, bf_hi(p.x));
    atomicAdd(q + 2, bf_lo(p.y)); atomicAdd(q + 3, bf_hi(p.y));
    atomicAdd(q + 4, bf_lo(p.z)); atomicAdd(q + 5, bf_hi(p.z));
    atomicAdd(q + 6, bf_lo(p.w)); atomicAdd(q + 7, bf_hi(p.w));
  }
}

// ---------- fused (concat + mean + GEMM + bias [+relu]) ----------
// out[n, j] = sum_{k<D} H[n,k]*W[j,k] + sum_{k<D} (S[n,k]*inv[n])*W[j,D+k] + b[j]
// One wave computes 16 nodes x DOUT outputs with mfma_f32_16x16x32_bf16.
// A-frag: A[m=lane&15][k=quad*8+j]; B-frag: B[k=quad*8+j][n=lane&15] = W[n][k];
// C/D: col=lane&15, row=quad*4+reg.
template<int D, int DOUT, bool RELU, bool OUTF32>
__global__ __launch_bounds__(256)
void sage_gemm(const unsigned short* __restrict__ H,  // N x D bf16
               const float* __restrict__ S,           // N x D fp32 (pre-mean sums)
               const float* __restrict__ invdeg,      // N
               const unsigned short* __restrict__ Wb, // DOUT x 2D bf16 row-major
               const float* __restrict__ bias,        // DOUT fp32
               void* __restrict__ outp) {             // N x DOUT
  const int K = 2 * D;
  int wave = (int)((blockIdx.x * 256 + threadIdx.x) >> 6);
  if (wave >= N_NODES / 16) return;
  int lane = threadIdx.x & 63;
  int l16  = lane & 15;
  int quad = lane >> 4;
  int n0   = wave * 16;
  int row  = n0 + l16;
  float inv = invdeg[row];
  const unsigned short* hrow = H + (size_t)row * D + quad * 8;
  const float*          srow = S + (size_t)row * D + quad * 8;
  floatx4 acc[DOUT / 16] = {};

  for (int k0 = 0; k0 < K; k0 += 32) {          // wave-uniform branch (D % 32 == 0)
    short8 a;
    if (k0 < D) {
      a = *(const short8*)(hrow + k0);
    } else {
      const float* sp = srow + (k0 - D);
      float4 s0 = *(const float4*)sp;
      float4 s1 = *(const float4*)(sp + 4);
      short8 t;
      t[0] = (short)f2bf(s0.x * inv); t[1] = (short)f2bf(s0.y * inv);
      t[2] = (short)f2bf(s0.z * inv); t[3] = (short)f2bf(s0.w * inv);
      t[4] = (short)f2bf(s1.x * inv); t[5] = (short)f2bf(s1.y * inv);
      t[6] = (short)f2bf(s1.z * inv); t[7] = (short)f2bf(s1.w * inv);
      a = t;
    }
#pragma unroll
    for (int jt = 0; jt < DOUT / 16; ++jt) {
      short8 b = *(const short8*)(Wb + (size_t)(jt * 16 + l16) * K + k0 + quad * 8);
      acc[jt] = __builtin_amdgcn_mfma_f32_16x16x32_bf16(a, b, acc[jt], 0, 0, 0);
    }
  }

#pragma unroll
  for (int jt = 0; jt < DOUT / 16; ++jt) {
    int j = jt * 16 + l16;
    float bj = bias[j];
#pragma unroll
    for (int r = 0; r < 4; ++r) {
      int node = n0 + quad * 4 + r;
      float v = acc[jt][r] + bj;
      if (RELU) v = fmaxf(v, 0.0f);
      if (OUTF32) ((float*)outp)[(size_t)node * DOUT + j] = v;
      else ((unsigned short*)outp)[(size_t)node * DOUT + j] = f2bf(v);
    }
  }
}

extern "C" void kernel_launch(void* const* d_in, const int* in_sizes, int n_in,
                              void* d_out, int out_size, void* d_ws, size_t ws_size,
                              hipStream_t stream) {
  const float* x  = (const float*)d_in[0];
  const int*   src = (const int*)d_in[1];
  const int*   dst = (const int*)d_in[2];
  const float* W1 = (const float*)d_in[3];
  const float* b1 = (const float*)d_in[4];
  const float* W2 = (const float*)d_in[5];
  const float* b2 = (const float*)d_in[6];
  const float* W3 = (const float*)d_in[7];
  const float* b3 = (const float*)d_in[8];

  char* ws = (char*)d_ws;
  unsigned short* H0 = (unsigned short*)ws; ws += (size_t)N_NODES * 256 * 2; // 51.2 MB
  unsigned short* H1 = (unsigned short*)ws; ws += (size_t)N_NODES * 256 * 2; // 51.2 MB
  float* S   = (float*)ws;                  ws += (size_t)N_NODES * 256 * 4; // 102.4 MB
  float* deg = (float*)ws;                  ws += 400128;                    // N fp32, padded
  unsigned short* Wb1 = (unsigned short*)ws; ws += 256 * 256 * 2;
  unsigned short* Wb2 = (unsigned short*)ws; ws += 256 * 512 * 2;
  unsigned short* Wb3 = (unsigned short*)ws; ws += 64 * 512 * 2;

  // conversions to bf16
  cvt_f32_bf16<<<(N_NODES * 128 / 4 + 255) / 256, 256, 0, stream>>>(x, H0, N_NODES * 128 / 4);
  cvt_f32_bf16<<<(256 * 256 / 4 + 255) / 256, 256, 0, stream>>>(W1, Wb1, 256 * 256 / 4);
  cvt_f32_bf16<<<(256 * 512 / 4 + 255) / 256, 256, 0, stream>>>(W2, Wb2, 256 * 512 / 4);
  cvt_f32_bf16<<<(64 * 512 / 4 + 255) / 256, 256, 0, stream>>>(W3, Wb3, 64 * 512 / 4);

  // degrees (shared across layers)
  hipMemsetAsync(deg, 0, (size_t)N_NODES * 4, stream);
  degree_kernel<<<(N_EDGES + 255) / 256, 256, 0, stream>>>(dst, deg);
  inv_kernel<<<(N_NODES + 255) / 256, 256, 0, stream>>>(deg);

  // ---- layer 1: D=128 -> 256, relu, bf16 out (H1) ----
  hipMemsetAsync(S, 0, (size_t)N_NODES * 128 * 4, stream);
  scatter_kernel<128, 1><<<N_EDGES / 256, 256, 0, stream>>>(H0, src, dst, S);
  sage_gemm<128, 256, true, false><<<(6250 + 3) / 4, 256, 0, stream>>>(H0, S, deg, Wb1, b1, H1);

  // ---- layer 2: D=256 -> 256, relu, bf16 out (H0) ----
  hipMemsetAsync(S, 0, (size_t)N_NODES * 256 * 4, stream);
  scatter_kernel<256, 2><<<N_EDGES * 2 / 256, 256, 0, stream>>>(H1, src, dst, S);
  sage_gemm<256, 256, true, false><<<(6250 + 3) / 4, 256, 0, stream>>>(H1, S, deg, Wb2, b2, H0);

  // ---- layer 3: D=256 -> 64, no relu, fp32 out ----
  hipMemsetAsync(S, 0, (size_t)N_NODES * 256 * 4, stream);
  scatter_kernel<256, 2><<<N_EDGES * 2 / 256, 256, 0, stream>>>(H0, src, dst, S);
  sage_gemm<256, 64, false, true><<<(6250 + 3) / 4, 256, 0, stream>>>(H0, S, deg, Wb3, b3, (float*)d_out);
}

// Round 2
// 1271.271 us; speedup vs baseline: 43.8514x; 43.8514x over previous
//
#include <hip/hip_runtime.h>
#include <hip/hip_bf16.h>
#include <cstdint>
#include <cstddef>

#define N_NODES 100000
#define N_EDGES 1600000

typedef __attribute__((ext_vector_type(8))) short short8;
typedef __attribute__((ext_vector_type(4))) float floatx4;

__device__ inline float bf_lo(unsigned int u) { return __uint_as_float(u << 16); }
__device__ inline float bf_hi(unsigned int u) { return __uint_as_float(u & 0xffff0000u); }
__device__ inline unsigned short f2bf(float f) {
  unsigned int u = __float_as_uint(f);
  u += 0x7fffu + ((u >> 16) & 1u);   // round-nearest-even
  return (unsigned short)(u >> 16);
}

// ---------- fp32 -> bf16 conversion, 4 elems/thread ----------
__global__ void cvt_f32_bf16(const float* __restrict__ in,
                             unsigned short* __restrict__ out, int n4) {
  int t = blockIdx.x * blockDim.x + threadIdx.x;
  if (t >= n4) return;
  float4 v = ((const float4*)in)[t];
  ushort4 o;
  o.x = f2bf(v.x); o.y = f2bf(v.y); o.z = f2bf(v.z); o.w = f2bf(v.w);
  ((ushort4*)out)[t] = o;
}

// ---------- CSR build: histogram -> scan -> fill ----------
__global__ void hist_kernel(const int* __restrict__ dst, int* __restrict__ count) {
  int e = blockIdx.x * blockDim.x + threadIdx.x;
  if (e < N_EDGES) atomicAdd(count + dst[e], 1);
}

__global__ __launch_bounds__(1024)
void scan_kernel(const int* __restrict__ count, int* __restrict__ start,
                 int* __restrict__ cursor, float* __restrict__ invdeg) {
  __shared__ int part[1024];
  const int CH = (N_NODES + 1023) / 1024;   // 98
  int t = threadIdx.x;
  int lo = t * CH, hi = min(lo + CH, N_NODES);
  int s = 0;
  for (int i = lo; i < hi; ++i) s += count[i];
  part[t] = s;
  __syncthreads();
  if (t == 0) {
    int run = 0;
    for (int i = 0; i < 1024; ++i) { int v = part[i]; part[i] = run; run += v; }
  }
  __syncthreads();
  int run = part[t];
  for (int i = lo; i < hi; ++i) {
    start[i] = run; cursor[i] = run;
    int c = count[i];
    invdeg[i] = 1.0f / fmaxf((float)c, 1.0f);
    run += c;
  }
  if (t == 1023) start[N_NODES] = N_EDGES;
}

__global__ void fill_kernel(const int* __restrict__ src, const int* __restrict__ dst,
                            int* __restrict__ cursor, int* __restrict__ esrc) {
  int e = blockIdx.x * blockDim.x + threadIdx.x;
  if (e < N_EDGES) {
    int pos = atomicAdd(cursor + dst[e], 1);
    esrc[pos] = src[e];
  }
}

// ---------- gather-mean: hn[n] = mean over incoming edges of h[src] ----------
// One wave per dst node; lane owns D/64 contiguous feats; 4-deep manual unroll
// keeps 4 independent row-gathers in flight.
template<int D>
__global__ __launch_bounds__(256)
void gather_mean(const unsigned short* __restrict__ h,
                 const int* __restrict__ start,
                 const int* __restrict__ esrc,
                 const float* __restrict__ invdeg,
                 unsigned short* __restrict__ hn) {
  int wave = (int)((blockIdx.x * 256 + threadIdx.x) >> 6);
  if (wave >= N_NODES) return;
  int lane = threadIdx.x & 63;
  int s0 = start[wave], s1 = start[wave + 1];
  constexpr int FPL = D / 64;           // 2 (D=128) or 4 (D=256)
  float acc[FPL] = {};
  const unsigned short* base = h + lane * FPL;

  int e = s0;
  if constexpr (FPL == 4) {
    for (; e + 4 <= s1; e += 4) {
      int sn0 = esrc[e], sn1 = esrc[e + 1], sn2 = esrc[e + 2], sn3 = esrc[e + 3];
      uint2 p0 = *(const uint2*)(base + (size_t)sn0 * D);
      uint2 p1 = *(const uint2*)(base + (size_t)sn1 * D);
      uint2 p2 = *(const uint2*)(base + (size_t)sn2 * D);
      uint2 p3 = *(const uint2*)(base + (size_t)sn3 * D);
      acc[0] += bf_lo(p0.x) + bf_lo(p1.x) + bf_lo(p2.x) + bf_lo(p3.x);
      acc[1] += bf_hi(p0.x) + bf_hi(p1.x) + bf_hi(p2.x) + bf_hi(p3.x);
      acc[2] += bf_lo(p0.y) + bf_lo(p1.y) + bf_lo(p2.y) + bf_lo(p3.y);
      acc[3] += bf_hi(p0.y) + bf_hi(p1.y) + bf_hi(p2.y) + bf_hi(p3.y);
    }
    for (; e < s1; ++e) {
      int sn = esrc[e];
      uint2 p = *(const uint2*)(base + (size_t)sn * D);
      acc[0] += bf_lo(p.x); acc[1] += bf_hi(p.x);
      acc[2] += bf_lo(p.y); acc[3] += bf_hi(p.y);
    }
  } else {
    for (; e + 4 <= s1; e += 4) {
      int sn0 = esrc[e], sn1 = esrc[e + 1], sn2 = esrc[e + 2], sn3 = esrc[e + 3];
      unsigned int p0 = *(const unsigned int*)(base + (size_t)sn0 * D);
      unsigned int p1 = *(const unsigned int*)(base + (size_t)sn1 * D);
      unsigned int p2 = *(const unsigned int*)(base + (size_t)sn2 * D);
      unsigned int p3 = *(const unsigned int*)(base + (size_t)sn3 * D);
      acc[0] += bf_lo(p0) + bf_lo(p1) + bf_lo(p2) + bf_lo(p3);
      acc[1] += bf_hi(p0) + bf_hi(p1) + bf_hi(p2) + bf_hi(p3);
    }
    for (; e < s1; ++e) {
      int sn = esrc[e];
      unsigned int p = *(const unsigned int*)(base + (size_t)sn * D);
      acc[0] += bf_lo(p); acc[1] += bf_hi(p);
    }
  }

  float inv = invdeg[wave];
  unsigned short* out = hn + (size_t)wave * D + lane * FPL;
  if constexpr (FPL == 4) {
    ushort4 o;
    o.x = f2bf(acc[0] * inv); o.y = f2bf(acc[1] * inv);
    o.z = f2bf(acc[2] * inv); o.w = f2bf(acc[3] * inv);
    *(ushort4*)out = o;
  } else {
    ushort2 o;
    o.x = f2bf(acc[0] * inv); o.y = f2bf(acc[1] * inv);
    *(ushort2*)out = o;
  }
}

// ---------- fused (concat + GEMM + bias [+relu]) ----------
// out[n, j] = sum_{k<D} H[n,k]*W[j,k] + sum_{k<D} HN[n,k]*W[j,D+k] + b[j]
// One wave computes 16 nodes x DOUT outputs with mfma_f32_16x16x32_bf16.
// A-frag: A[m=lane&15][k=quad*8+j]; B-frag: B[k=quad*8+j][n=lane&15] = W[n][k];
// C/D: col=lane&15, row=quad*4+reg.
template<int D, int DOUT, bool RELU, bool OUTF32>
__global__ __launch_bounds__(256)
void sage_gemm(const unsigned short* __restrict__ H,   // N x D bf16 (self)
               const unsigned short* __restrict__ HN,  // N x D bf16 (neigh mean)
               const unsigned short* __restrict__ Wb,  // DOUT x 2D bf16 row-major
               const float* __restrict__ bias,         // DOUT fp32
               void* __restrict__ outp) {              // N x DOUT
  const int K = 2 * D;
  int wave = (int)((blockIdx.x * 256 + threadIdx.x) >> 6);
  if (wave >= N_NODES / 16) return;
  int lane = threadIdx.x & 63;
  int l16  = lane & 15;
  int quad = lane >> 4;
  int n0   = wave * 16;
  int row  = n0 + l16;
  const unsigned short* hrow  = H  + (size_t)row * D + quad * 8;
  const unsigned short* hnrow = HN + (size_t)row * D + quad * 8;
  floatx4 acc[DOUT / 16] = {};

  for (int k0 = 0; k0 < K; k0 += 32) {   // wave-uniform branch (D % 32 == 0)
    short8 a = (k0 < D) ? *(const short8*)(hrow + k0)
                        : *(const short8*)(hnrow + (k0 - D));
#pragma unroll
    for (int jt = 0; jt < DOUT / 16; ++jt) {
      short8 b = *(const short8*)(Wb + (size_t)(jt * 16 + l16) * K + k0 + quad * 8);
      acc[jt] = __builtin_amdgcn_mfma_f32_16x16x32_bf16(a, b, acc[jt], 0, 0, 0);
    }
  }

#pragma unroll
  for (int jt = 0; jt < DOUT / 16; ++jt) {
    int j = jt * 16 + l16;
    float bj = bias[j];
#pragma unroll
    for (int r = 0; r < 4; ++r) {
      int node = n0 + quad * 4 + r;
      float v = acc[jt][r] + bj;
      if (RELU) v = fmaxf(v, 0.0f);
      if (OUTF32) ((float*)outp)[(size_t)node * DOUT + j] = v;
      else ((unsigned short*)outp)[(size_t)node * DOUT + j] = f2bf(v);
    }
  }
}

extern "C" void kernel_launch(void* const* d_in, const int* in_sizes, int n_in,
                              void* d_out, int out_size, void* d_ws, size_t ws_size,
                              hipStream_t stream) {
  const float* x   = (const float*)d_in[0];
  const int*   src = (const int*)d_in[1];
  const int*   dst = (const int*)d_in[2];
  const float* W1 = (const float*)d_in[3];
  const float* b1 = (const float*)d_in[4];
  const float* W2 = (const float*)d_in[5];
  const float* b2 = (const float*)d_in[6];
  const float* W3 = (const float*)d_in[7];
  const float* b3 = (const float*)d_in[8];

  char* ws = (char*)d_ws;
  unsigned short* H0 = (unsigned short*)ws; ws += (size_t)N_NODES * 128 * 2; // 25.6 MB
  unsigned short* H1 = (unsigned short*)ws; ws += (size_t)N_NODES * 256 * 2; // 51.2 MB
  unsigned short* H2 = (unsigned short*)ws; ws += (size_t)N_NODES * 256 * 2; // 51.2 MB
  unsigned short* HN = (unsigned short*)ws; ws += (size_t)N_NODES * 256 * 2; // 51.2 MB
  int* count  = (int*)ws;  ws += (size_t)(N_NODES + 32) * 4;
  int* startp = (int*)ws;  ws += (size_t)(N_NODES + 32) * 4;
  int* cursor = (int*)ws;  ws += (size_t)(N_NODES + 32) * 4;
  int* esrc   = (int*)ws;  ws += (size_t)N_EDGES * 4;                        // 6.4 MB
  float* invdeg = (float*)ws; ws += (size_t)(N_NODES + 32) * 4;
  unsigned short* Wb1 = (unsigned short*)ws; ws += 256 * 256 * 2;
  unsigned short* Wb2 = (unsigned short*)ws; ws += 256 * 512 * 2;
  unsigned short* Wb3 = (unsigned short*)ws; ws += 64 * 512 * 2;

  // CSR build (shared across all 3 layers)
  hipMemsetAsync(count, 0, (size_t)N_NODES * 4, stream);
  hist_kernel<<<(N_EDGES + 255) / 256, 256, 0, stream>>>(dst, count);
  scan_kernel<<<1, 1024, 0, stream>>>(count, startp, cursor, invdeg);
  fill_kernel<<<(N_EDGES + 255) / 256, 256, 0, stream>>>(src, dst, cursor, esrc);

  // conversions to bf16
  cvt_f32_bf16<<<(N_NODES * 128 / 4 + 255) / 256, 256, 0, stream>>>(x, H0, N_NODES * 128 / 4);
  cvt_f32_bf16<<<(256 * 256 / 4 + 255) / 256, 256, 0, stream>>>(W1, Wb1, 256 * 256 / 4);
  cvt_f32_bf16<<<(256 * 512 / 4 + 255) / 256, 256, 0, stream>>>(W2, Wb2, 256 * 512 / 4);
  cvt_f32_bf16<<<(64 * 512 / 4 + 255) / 256, 256, 0, stream>>>(W3, Wb3, 64 * 512 / 4);

  const int GGRID = (N_NODES * 64 + 255) / 256;    // one wave per node
  const int MGRID = (N_NODES / 16 + 3) / 4;        // one wave per 16 nodes

  // ---- layer 1: D=128 -> 256, relu ----
  gather_mean<128><<<GGRID, 256, 0, stream>>>(H0, startp, esrc, invdeg, HN);
  sage_gemm<128, 256, true, false><<<MGRID, 256, 0, stream>>>(H0, HN, Wb1, b1, H1);

  // ---- layer 2: D=256 -> 256, relu ----
  gather_mean<256><<<GGRID, 256, 0, stream>>>(H1, startp, esrc, invdeg, HN);
  sage_gemm<256, 256, true, false><<<MGRID, 256, 0, stream>>>(H1, HN, Wb2, b2, H2);

  // ---- layer 3: D=256 -> 64, no relu, fp32 out ----
  gather_mean<256><<<GGRID, 256, 0, stream>>>(H2, startp, esrc, invdeg, HN);
  sage_gemm<256, 64, false, true><<<MGRID, 256, 0, stream>>>(H2, HN, Wb3, b3, (float*)d_out);
}

// Round 3
// 996.403 us; speedup vs baseline: 55.9482x; 1.2759x over previous
//
#include <hip/hip_runtime.h>
#include <hip/hip_bf16.h>
#include <cstdint>
#include <cstddef>

#define N_NODES 100000
#define N_EDGES 1600000
#define NB_SCAN ((N_NODES + 255) / 256)   // 391

typedef __attribute__((ext_vector_type(8))) short short8;
typedef __attribute__((ext_vector_type(4))) float floatx4;

__device__ inline float bf_lo(unsigned int u) { return __uint_as_float(u << 16); }
__device__ inline float bf_hi(unsigned int u) { return __uint_as_float(u & 0xffff0000u); }
__device__ inline unsigned short f2bf(float f) {
  unsigned int u = __float_as_uint(f);
  u += 0x7fffu + ((u >> 16) & 1u);   // round-nearest-even
  return (unsigned short)(u >> 16);
}

// ---------- fp32 -> bf16 conversion, 4 elems/thread ----------
__global__ void cvt_f32_bf16(const float* __restrict__ in,
                             unsigned short* __restrict__ out, int n4) {
  int t = blockIdx.x * blockDim.x + threadIdx.x;
  if (t >= n4) return;
  float4 v = ((const float4*)in)[t];
  ushort4 o;
  o.x = f2bf(v.x); o.y = f2bf(v.y); o.z = f2bf(v.z); o.w = f2bf(v.w);
  ((ushort4*)out)[t] = o;
}

// ---------- CSR build: histogram -> hierarchical scan -> fill ----------
__global__ void hist_kernel(const int* __restrict__ dst, int* __restrict__ count) {
  int e = blockIdx.x * blockDim.x + threadIdx.x;
  if (e < N_EDGES) atomicAdd(count + dst[e], 1);
}

__device__ inline int wave_incl_scan(int v, int lane) {
#pragma unroll
  for (int off = 1; off < 64; off <<= 1) {
    int t = __shfl_up(v, off, 64);
    if (lane >= off) v += t;
  }
  return v;
}

// stage 1: per-block sums of count[]
__global__ __launch_bounds__(256)
void scan1_kernel(const int* __restrict__ count, int* __restrict__ bsum) {
  __shared__ int lds[4];
  int i = blockIdx.x * 256 + threadIdx.x;
  int v = (i < N_NODES) ? count[i] : 0;
  int lane = threadIdx.x & 63, wid = threadIdx.x >> 6;
#pragma unroll
  for (int off = 32; off; off >>= 1) v += __shfl_down(v, off, 64);
  if (lane == 0) lds[wid] = v;
  __syncthreads();
  if (threadIdx.x == 0) bsum[blockIdx.x] = lds[0] + lds[1] + lds[2] + lds[3];
}

// stage 2: exclusive scan of the 391 block sums (one block)
__global__ __launch_bounds__(512)
void scan2_kernel(const int* __restrict__ bsum, int* __restrict__ boff,
                  int* __restrict__ start) {
  __shared__ int lds[8];
  int t = threadIdx.x, lane = t & 63, wid = t >> 6;
  int v = (t < NB_SCAN) ? bsum[t] : 0;
  int incl = wave_incl_scan(v, lane);
  if (lane == 63) lds[wid] = incl;
  __syncthreads();
  int woff = 0;
  for (int i = 0; i < wid; ++i) woff += lds[i];
  if (t < NB_SCAN) boff[t] = woff + incl - v;
  if (t == 0) start[N_NODES] = N_EDGES;
}

// stage 3: intra-block exclusive scan + global offset -> start/cursor/invdeg
__global__ __launch_bounds__(256)
void scan3_kernel(const int* __restrict__ count, const int* __restrict__ boff,
                  int* __restrict__ start, int* __restrict__ cursor,
                  float* __restrict__ invdeg) {
  __shared__ int lds[4];
  int i = blockIdx.x * 256 + threadIdx.x;
  int v = (i < N_NODES) ? count[i] : 0;
  int lane = threadIdx.x & 63, wid = threadIdx.x >> 6;
  int incl = wave_incl_scan(v, lane);
  if (lane == 63) lds[wid] = incl;
  __syncthreads();
  int woff = 0;
  for (int w = 0; w < wid; ++w) woff += lds[w];
  if (i < N_NODES) {
    int s = boff[blockIdx.x] + woff + incl - v;
    start[i] = s; cursor[i] = s;
    invdeg[i] = 1.0f / fmaxf((float)v, 1.0f);
  }
}

__global__ void fill_kernel(const int* __restrict__ src, const int* __restrict__ dst,
                            int* __restrict__ cursor, int* __restrict__ esrc) {
  int e = blockIdx.x * blockDim.x + threadIdx.x;
  if (e < N_EDGES) {
    int pos = atomicAdd(cursor + dst[e], 1);
    esrc[pos] = src[e];
  }
}

// ---------- gather-mean: hn[n] = mean over incoming edges of h[src] ----------
// One wave per dst node; lane owns D/64 contiguous feats; 4-deep manual unroll
// keeps 4 independent row-gathers in flight.
template<int D>
__global__ __launch_bounds__(256)
void gather_mean(const unsigned short* __restrict__ h,
                 const int* __restrict__ start,
                 const int* __restrict__ esrc,
                 const float* __restrict__ invdeg,
                 unsigned short* __restrict__ hn) {
  int wave = (int)((blockIdx.x * 256 + threadIdx.x) >> 6);
  if (wave >= N_NODES) return;
  int lane = threadIdx.x & 63;
  int s0 = start[wave], s1 = start[wave + 1];
  constexpr int FPL = D / 64;           // 2 (D=128) or 4 (D=256)
  float acc[FPL] = {};
  const unsigned short* base = h + lane * FPL;

  int e = s0;
  if constexpr (FPL == 4) {
    for (; e + 4 <= s1; e += 4) {
      int sn0 = esrc[e], sn1 = esrc[e + 1], sn2 = esrc[e + 2], sn3 = esrc[e + 3];
      uint2 p0 = *(const uint2*)(base + (size_t)sn0 * D);
      uint2 p1 = *(const uint2*)(base + (size_t)sn1 * D);
      uint2 p2 = *(const uint2*)(base + (size_t)sn2 * D);
      uint2 p3 = *(const uint2*)(base + (size_t)sn3 * D);
      acc[0] += bf_lo(p0.x) + bf_lo(p1.x) + bf_lo(p2.x) + bf_lo(p3.x);
      acc[1] += bf_hi(p0.x) + bf_hi(p1.x) + bf_hi(p2.x) + bf_hi(p3.x);
      acc[2] += bf_lo(p0.y) + bf_lo(p1.y) + bf_lo(p2.y) + bf_lo(p3.y);
      acc[3] += bf_hi(p0.y) + bf_hi(p1.y) + bf_hi(p2.y) + bf_hi(p3.y);
    }
    for (; e < s1; ++e) {
      int sn = esrc[e];
      uint2 p = *(const uint2*)(base + (size_t)sn * D);
      acc[0] += bf_lo(p.x); acc[1] += bf_hi(p.x);
      acc[2] += bf_lo(p.y); acc[3] += bf_hi(p.y);
    }
  } else {
    for (; e + 4 <= s1; e += 4) {
      int sn0 = esrc[e], sn1 = esrc[e + 1], sn2 = esrc[e + 2], sn3 = esrc[e + 3];
      unsigned int p0 = *(const unsigned int*)(base + (size_t)sn0 * D);
      unsigned int p1 = *(const unsigned int*)(base + (size_t)sn1 * D);
      unsigned int p2 = *(const unsigned int*)(base + (size_t)sn2 * D);
      unsigned int p3 = *(const unsigned int*)(base + (size_t)sn3 * D);
      acc[0] += bf_lo(p0) + bf_lo(p1) + bf_lo(p2) + bf_lo(p3);
      acc[1] += bf_hi(p0) + bf_hi(p1) + bf_hi(p2) + bf_hi(p3);
    }
    for (; e < s1; ++e) {
      int sn = esrc[e];
      unsigned int p = *(const unsigned int*)(base + (size_t)sn * D);
      acc[0] += bf_lo(p); acc[1] += bf_hi(p);
    }
  }

  float inv = invdeg[wave];
  unsigned short* out = hn + (size_t)wave * D + lane * FPL;
  if constexpr (FPL == 4) {
    ushort4 o;
    o.x = f2bf(acc[0] * inv); o.y = f2bf(acc[1] * inv);
    o.z = f2bf(acc[2] * inv); o.w = f2bf(acc[3] * inv);
    *(ushort4*)out = o;
  } else {
    ushort2 o;
    o.x = f2bf(acc[0] * inv); o.y = f2bf(acc[1] * inv);
    *(ushort2*)out = o;
  }
}

// ---------- fused (concat + GEMM + bias [+relu]) ----------
// out[n, j] = sum_{k<D} H[n,k]*W[j,k] + sum_{k<D} HN[n,k]*W[j,D+k] + b[j]
// One wave computes 16 nodes x DOUT outputs with mfma_f32_16x16x32_bf16.
// A-frag: A[m=lane&15][k=quad*8+j]; B-frag: B[k=quad*8+j][n=lane&15] = W[n][k];
// C/D: col=lane&15, row=quad*4+reg.
template<int D, int DOUT, bool RELU, bool OUTF32>
__global__ __launch_bounds__(256)
void sage_gemm(const unsigned short* __restrict__ H,   // N x D bf16 (self)
               const unsigned short* __restrict__ HN,  // N x D bf16 (neigh mean)
               const unsigned short* __restrict__ Wb,  // DOUT x 2D bf16 row-major
               const float* __restrict__ bias,         // DOUT fp32
               void* __restrict__ outp) {              // N x DOUT
  const int K = 2 * D;
  int wave = (int)((blockIdx.x * 256 + threadIdx.x) >> 6);
  if (wave >= N_NODES / 16) return;
  int lane = threadIdx.x & 63;
  int l16  = lane & 15;
  int quad = lane >> 4;
  int n0   = wave * 16;
  int row  = n0 + l16;
  const unsigned short* hrow  = H  + (size_t)row * D + quad * 8;
  const unsigned short* hnrow = HN + (size_t)row * D + quad * 8;
  floatx4 acc[DOUT / 16] = {};

  for (int k0 = 0; k0 < K; k0 += 32) {   // wave-uniform branch (D % 32 == 0)
    short8 a = (k0 < D) ? *(const short8*)(hrow + k0)
                        : *(const short8*)(hnrow + (k0 - D));
#pragma unroll
    for (int jt = 0; jt < DOUT / 16; ++jt) {
      short8 b = *(const short8*)(Wb + (size_t)(jt * 16 + l16) * K + k0 + quad * 8);
      acc[jt] = __builtin_amdgcn_mfma_f32_16x16x32_bf16(a, b, acc[jt], 0, 0, 0);
    }
  }

#pragma unroll
  for (int jt = 0; jt < DOUT / 16; ++jt) {
    int j = jt * 16 + l16;
    float bj = bias[j];
#pragma unroll
    for (int r = 0; r < 4; ++r) {
      int node = n0 + quad * 4 + r;
      float v = acc[jt][r] + bj;
      if (RELU) v = fmaxf(v, 0.0f);
      if (OUTF32) ((float*)outp)[(size_t)node * DOUT + j] = v;
      else ((unsigned short*)outp)[(size_t)node * DOUT + j] = f2bf(v);
    }
  }
}

extern "C" void kernel_launch(void* const* d_in, const int* in_sizes, int n_in,
                              void* d_out, int out_size, void* d_ws, size_t ws_size,
                              hipStream_t stream) {
  const float* x   = (const float*)d_in[0];
  const int*   src = (const int*)d_in[1];
  const int*   dst = (const int*)d_in[2];
  const float* W1 = (const float*)d_in[3];
  const float* b1 = (const float*)d_in[4];
  const float* W2 = (const float*)d_in[5];
  const float* b2 = (const float*)d_in[6];
  const float* W3 = (const float*)d_in[7];
  const float* b3 = (const float*)d_in[8];

  char* ws = (char*)d_ws;
  unsigned short* H0 = (unsigned short*)ws; ws += (size_t)N_NODES * 128 * 2; // 25.6 MB
  unsigned short* H1 = (unsigned short*)ws; ws += (size_t)N_NODES * 256 * 2; // 51.2 MB
  unsigned short* H2 = (unsigned short*)ws; ws += (size_t)N_NODES * 256 * 2; // 51.2 MB
  unsigned short* HN = (unsigned short*)ws; ws += (size_t)N_NODES * 256 * 2; // 51.2 MB
  int* count  = (int*)ws;  ws += (size_t)(N_NODES + 32) * 4;
  int* startp = (int*)ws;  ws += (size_t)(N_NODES + 32) * 4;
  int* cursor = (int*)ws;  ws += (size_t)(N_NODES + 32) * 4;
  int* esrc   = (int*)ws;  ws += (size_t)N_EDGES * 4;                        // 6.4 MB
  float* invdeg = (float*)ws; ws += (size_t)(N_NODES + 32) * 4;
  int* bsum = (int*)ws;    ws += (size_t)(NB_SCAN + 32) * 4;
  int* boff = (int*)ws;    ws += (size_t)(NB_SCAN + 32) * 4;
  unsigned short* Wb1 = (unsigned short*)ws; ws += 256 * 256 * 2;
  unsigned short* Wb2 = (unsigned short*)ws; ws += 256 * 512 * 2;
  unsigned short* Wb3 = (unsigned short*)ws; ws += 64 * 512 * 2;

  // CSR build (shared across all 3 layers)
  hipMemsetAsync(count, 0, (size_t)N_NODES * 4, stream);
  hist_kernel<<<(N_EDGES + 255) / 256, 256, 0, stream>>>(dst, count);
  scan1_kernel<<<NB_SCAN, 256, 0, stream>>>(count, bsum);
  scan2_kernel<<<1, 512, 0, stream>>>(bsum, boff, startp);
  scan3_kernel<<<NB_SCAN, 256, 0, stream>>>(count, boff, startp, cursor, invdeg);
  fill_kernel<<<(N_EDGES + 255) / 256, 256, 0, stream>>>(src, dst, cursor, esrc);

  // conversions to bf16
  cvt_f32_bf16<<<(N_NODES * 128 / 4 + 255) / 256, 256, 0, stream>>>(x, H0, N_NODES * 128 / 4);
  cvt_f32_bf16<<<(256 * 256 / 4 + 255) / 256, 256, 0, stream>>>(W1, Wb1, 256 * 256 / 4);
  cvt_f32_bf16<<<(256 * 512 / 4 + 255) / 256, 256, 0, stream>>>(W2, Wb2, 256 * 512 / 4);
  cvt_f32_bf16<<<(64 * 512 / 4 + 255) / 256, 256, 0, stream>>>(W3, Wb3, 64 * 512 / 4);

  const int GGRID = (N_NODES * 64 + 255) / 256;    // one wave per node
  const int MGRID = (N_NODES / 16 + 3) / 4;        // one wave per 16 nodes

  // ---- layer 1: D=128 -> 256, relu ----
  gather_mean<128><<<GGRID, 256, 0, stream>>>(H0, startp, esrc, invdeg, HN);
  sage_gemm<128, 256, true, false><<<MGRID, 256, 0, stream>>>(H0, HN, Wb1, b1, H1);

  // ---- layer 2: D=256 -> 256, relu ----
  gather_mean<256><<<GGRID, 256, 0, stream>>>(H1, startp, esrc, invdeg, HN);
  sage_gemm<256, 256, true, false><<<MGRID, 256, 0, stream>>>(H1, HN, Wb2, b2, H2);

  // ---- layer 3: D=256 -> 64, no relu, fp32 out ----
  gather_mean<256><<<GGRID, 256, 0, stream>>>(H2, startp, esrc, invdeg, HN);
  sage_gemm<256, 64, false, true><<<MGRID, 256, 0, stream>>>(H2, HN, Wb3, b3, (float*)d_out);
}

// Round 4
// 854.522 us; speedup vs baseline: 65.2376x; 1.1660x over previous
//
#include <hip/hip_runtime.h>
#include <hip/hip_bf16.h>
#include <cstdint>
#include <cstddef>

#define N_NODES 100000
#define N_EDGES 1600000
#define NB_SCAN ((N_NODES + 255) / 256)   // 391

typedef __attribute__((ext_vector_type(8))) short short8;
typedef __attribute__((ext_vector_type(4))) float floatx4;

__device__ inline float bf_lo(unsigned int u) { return __uint_as_float(u << 16); }
__device__ inline float bf_hi(unsigned int u) { return __uint_as_float(u & 0xffff0000u); }
__device__ inline unsigned short f2bf(float f) {
  unsigned int u = __float_as_uint(f);
  u += 0x7fffu + ((u >> 16) & 1u);   // round-nearest-even
  return (unsigned short)(u >> 16);
}

// ---------- fp32 -> bf16 conversion, 4 elems/thread ----------
__global__ void cvt_f32_bf16(const float* __restrict__ in,
                             unsigned short* __restrict__ out, int n4) {
  int t = blockIdx.x * blockDim.x + threadIdx.x;
  if (t >= n4) return;
  float4 v = ((const float4*)in)[t];
  ushort4 o;
  o.x = f2bf(v.x); o.y = f2bf(v.y); o.z = f2bf(v.z); o.w = f2bf(v.w);
  ((ushort4*)out)[t] = o;
}

// ---------- CSR build: histogram -> hierarchical scan -> fill ----------
__global__ void hist_kernel(const int* __restrict__ dst, int* __restrict__ count) {
  int e = blockIdx.x * blockDim.x + threadIdx.x;
  if (e < N_EDGES) atomicAdd(count + dst[e], 1);
}

__device__ inline int wave_incl_scan(int v, int lane) {
#pragma unroll
  for (int off = 1; off < 64; off <<= 1) {
    int t = __shfl_up(v, off, 64);
    if (lane >= off) v += t;
  }
  return v;
}

// stage 1: per-block sums of count[]
__global__ __launch_bounds__(256)
void scan1_kernel(const int* __restrict__ count, int* __restrict__ bsum) {
  __shared__ int lds[4];
  int i = blockIdx.x * 256 + threadIdx.x;
  int v = (i < N_NODES) ? count[i] : 0;
  int lane = threadIdx.x & 63, wid = threadIdx.x >> 6;
#pragma unroll
  for (int off = 32; off; off >>= 1) v += __shfl_down(v, off, 64);
  if (lane == 0) lds[wid] = v;
  __syncthreads();
  if (threadIdx.x == 0) bsum[blockIdx.x] = lds[0] + lds[1] + lds[2] + lds[3];
}

// stage 2: exclusive scan of the 391 block sums (one block)
__global__ __launch_bounds__(512)
void scan2_kernel(const int* __restrict__ bsum, int* __restrict__ boff,
                  int* __restrict__ start) {
  __shared__ int lds[8];
  int t = threadIdx.x, lane = t & 63, wid = t >> 6;
  int v = (t < NB_SCAN) ? bsum[t] : 0;
  int incl = wave_incl_scan(v, lane);
  if (lane == 63) lds[wid] = incl;
  __syncthreads();
  int woff = 0;
  for (int i = 0; i < wid; ++i) woff += lds[i];
  if (t < NB_SCAN) boff[t] = woff + incl - v;
  if (t == 0) start[N_NODES] = N_EDGES;
}

// stage 3: intra-block exclusive scan + global offset -> start/cursor/invdeg
__global__ __launch_bounds__(256)
void scan3_kernel(const int* __restrict__ count, const int* __restrict__ boff,
                  int* __restrict__ start, int* __restrict__ cursor,
                  float* __restrict__ invdeg) {
  __shared__ int lds[4];
  int i = blockIdx.x * 256 + threadIdx.x;
  int v = (i < N_NODES) ? count[i] : 0;
  int lane = threadIdx.x & 63, wid = threadIdx.x >> 6;
  int incl = wave_incl_scan(v, lane);
  if (lane == 63) lds[wid] = incl;
  __syncthreads();
  int woff = 0;
  for (int w = 0; w < wid; ++w) woff += lds[w];
  if (i < N_NODES) {
    int s = boff[blockIdx.x] + woff + incl - v;
    start[i] = s; cursor[i] = s;
    invdeg[i] = 1.0f / fmaxf((float)v, 1.0f);
  }
}

__global__ void fill_kernel(const int* __restrict__ src, const int* __restrict__ dst,
                            int* __restrict__ cursor, int* __restrict__ esrc) {
  int e = blockIdx.x * blockDim.x + threadIdx.x;
  if (e < N_EDGES) {
    int pos = atomicAdd(cursor + dst[e], 1);
    esrc[pos] = src[e];
  }
}

// ---------- gather-mean: hn[n] = mean over incoming edges of h[src] ----------
template<int D>
__global__ __launch_bounds__(256)
void gather_mean(const unsigned short* __restrict__ h,
                 const int* __restrict__ start,
                 const int* __restrict__ esrc,
                 const float* __restrict__ invdeg,
                 unsigned short* __restrict__ hn) {
  int wave = (int)((blockIdx.x * 256 + threadIdx.x) >> 6);
  if (wave >= N_NODES) return;
  int lane = threadIdx.x & 63;
  int s0 = start[wave], s1 = start[wave + 1];
  constexpr int FPL = D / 64;           // 2 (D=128) or 4 (D=256)
  float acc[FPL] = {};
  const unsigned short* base = h + lane * FPL;

  int e = s0;
  if constexpr (FPL == 4) {
    for (; e + 4 <= s1; e += 4) {
      int sn0 = esrc[e], sn1 = esrc[e + 1], sn2 = esrc[e + 2], sn3 = esrc[e + 3];
      uint2 p0 = *(const uint2*)(base + (size_t)sn0 * D);
      uint2 p1 = *(const uint2*)(base + (size_t)sn1 * D);
      uint2 p2 = *(const uint2*)(base + (size_t)sn2 * D);
      uint2 p3 = *(const uint2*)(base + (size_t)sn3 * D);
      acc[0] += bf_lo(p0.x) + bf_lo(p1.x) + bf_lo(p2.x) + bf_lo(p3.x);
      acc[1] += bf_hi(p0.x) + bf_hi(p1.x) + bf_hi(p2.x) + bf_hi(p3.x);
      acc[2] += bf_lo(p0.y) + bf_lo(p1.y) + bf_lo(p2.y) + bf_lo(p3.y);
      acc[3] += bf_hi(p0.y) + bf_hi(p1.y) + bf_hi(p2.y) + bf_hi(p3.y);
    }
    for (; e < s1; ++e) {
      int sn = esrc[e];
      uint2 p = *(const uint2*)(base + (size_t)sn * D);
      acc[0] += bf_lo(p.x); acc[1] += bf_hi(p.x);
      acc[2] += bf_lo(p.y); acc[3] += bf_hi(p.y);
    }
  } else {
    for (; e + 4 <= s1; e += 4) {
      int sn0 = esrc[e], sn1 = esrc[e + 1], sn2 = esrc[e + 2], sn3 = esrc[e + 3];
      unsigned int p0 = *(const unsigned int*)(base + (size_t)sn0 * D);
      unsigned int p1 = *(const unsigned int*)(base + (size_t)sn1 * D);
      unsigned int p2 = *(const unsigned int*)(base + (size_t)sn2 * D);
      unsigned int p3 = *(const unsigned int*)(base + (size_t)sn3 * D);
      acc[0] += bf_lo(p0) + bf_lo(p1) + bf_lo(p2) + bf_lo(p3);
      acc[1] += bf_hi(p0) + bf_hi(p1) + bf_hi(p2) + bf_hi(p3);
    }
    for (; e < s1; ++e) {
      int sn = esrc[e];
      unsigned int p = *(const unsigned int*)(base + (size_t)sn * D);
      acc[0] += bf_lo(p); acc[1] += bf_hi(p);
    }
  }

  float inv = invdeg[wave];
  unsigned short* out = hn + (size_t)wave * D + lane * FPL;
  if constexpr (FPL == 4) {
    ushort4 o;
    o.x = f2bf(acc[0] * inv); o.y = f2bf(acc[1] * inv);
    o.z = f2bf(acc[2] * inv); o.w = f2bf(acc[3] * inv);
    *(ushort4*)out = o;
  } else {
    ushort2 o;
    o.x = f2bf(acc[0] * inv); o.y = f2bf(acc[1] * inv);
    *(ushort2*)out = o;
  }
}

// ---------- LDS-staged fused GEMM (concat + bias [+relu]) ----------
// Block = 4 waves. Tile BM x DOUT, K-chunks of 64 staged into LDS in
// fragment-swizzled layout via global_load_lds(16B): frag f occupies
// lds[f*1024B + lane*16B], exactly the mfma_f32_16x16x32_bf16 operand order
// (A[m=l16][k=quad*8+j], B[k=quad*8+j][n=l16]) verified in rounds 1-3.
// Wave computes WM x WN register tile: acc (WM/16)x(WN/16) frags.
template<int D, int DOUT, int BM, int WM, int WN, bool RELU, bool OUTF32>
__global__ __launch_bounds__(256)
void sage_gemm(const unsigned short* __restrict__ H,   // N x D bf16 (self)
               const unsigned short* __restrict__ HN,  // N x D bf16 (neigh mean)
               const unsigned short* __restrict__ Wb,  // DOUT x 2D bf16 row-major
               const float* __restrict__ bias,         // DOUT fp32
               void* __restrict__ outp) {              // N x DOUT
  constexpr int K   = 2 * D;
  constexpr int KC  = 64;            // K-chunk (divides D for D=128/256)
  constexpr int NMF = WM / 16;       // m-frags per wave
  constexpr int NJF = WN / 16;       // n-frags per wave
  constexpr int AF  = BM / 16;       // A frags per k0-half
  constexpr int BF  = DOUT / 16;     // B frags per k0-half
  constexpr int FRAGS = 2 * (AF + BF);
  constexpr int WAVES_N = DOUT / WN;

  __shared__ __align__(16) unsigned short lds[FRAGS * 512];  // FRAGS KB

  const int tid  = threadIdx.x;
  const int wave = tid >> 6, lane = tid & 63;
  const int l16  = lane & 15, quad = lane >> 4;
  const int n0   = blockIdx.x * BM;
  const int wm   = wave / WAVES_N;   // wave's m-tile index
  const int wn   = wave % WAVES_N;   // wave's n-tile index

  floatx4 acc[NMF][NJF] = {};

  for (int kc = 0; kc < K; kc += KC) {
    const unsigned short* srcH = (kc < D) ? H : HN;
    const int kbase = (kc < D) ? kc : kc - D;
    __syncthreads();                 // previous chunk's reads complete
#pragma unroll
    for (int f = wave; f < FRAGS; f += 4) {     // wave-uniform frag id
      int half = (f >= AF + BF) ? 1 : 0;
      int fi   = f - half * (AF + BF);
      const unsigned short* g;
      if (fi < AF) {                 // A frag, mi = fi
        int row = n0 + fi * 16 + l16;
        row = min(row, N_NODES - 1);
        g = srcH + (size_t)row * D + (kbase + half * 32 + quad * 8);
      } else {                       // B frag, jt = fi - AF
        int row = (fi - AF) * 16 + l16;
        g = Wb + (size_t)row * K + (kc + half * 32 + quad * 8);
      }
      __builtin_amdgcn_global_load_lds(
          (const __attribute__((address_space(1))) unsigned int*)g,
          (__attribute__((address_space(3))) unsigned int*)&lds[f * 512],
          16, 0, 0);
    }
    __syncthreads();                 // staging complete (drains vmcnt)
#pragma unroll
    for (int h = 0; h < 2; ++h) {    // two k0=32 halves per chunk
      short8 b[NJF];
#pragma unroll
      for (int jt = 0; jt < NJF; ++jt)
        b[jt] = *(const short8*)&lds[(h * (AF + BF) + AF + wn * NJF + jt) * 512 + lane * 8];
#pragma unroll
      for (int mi = 0; mi < NMF; ++mi) {
        short8 a = *(const short8*)&lds[(h * (AF + BF) + wm * NMF + mi) * 512 + lane * 8];
#pragma unroll
        for (int jt = 0; jt < NJF; ++jt)
          acc[mi][jt] = __builtin_amdgcn_mfma_f32_16x16x32_bf16(a, b[jt], acc[mi][jt], 0, 0, 0);
      }
    }
  }

  // epilogue: C/D layout col=l16, row=quad*4+r
#pragma unroll
  for (int mi = 0; mi < NMF; ++mi) {
#pragma unroll
    for (int jt = 0; jt < NJF; ++jt) {
      int j = wn * WN + jt * 16 + l16;
      float bj = bias[j];
#pragma unroll
      for (int r = 0; r < 4; ++r) {
        int node = n0 + wm * WM + mi * 16 + quad * 4 + r;
        if (node < N_NODES) {
          float v = acc[mi][jt][r] + bj;
          if (RELU) v = fmaxf(v, 0.0f);
          if (OUTF32) ((float*)outp)[(size_t)node * DOUT + j] = v;
          else ((unsigned short*)outp)[(size_t)node * DOUT + j] = f2bf(v);
        }
      }
    }
  }
}

extern "C" void kernel_launch(void* const* d_in, const int* in_sizes, int n_in,
                              void* d_out, int out_size, void* d_ws, size_t ws_size,
                              hipStream_t stream) {
  const float* x   = (const float*)d_in[0];
  const int*   src = (const int*)d_in[1];
  const int*   dst = (const int*)d_in[2];
  const float* W1 = (const float*)d_in[3];
  const float* b1 = (const float*)d_in[4];
  const float* W2 = (const float*)d_in[5];
  const float* b2 = (const float*)d_in[6];
  const float* W3 = (const float*)d_in[7];
  const float* b3 = (const float*)d_in[8];

  char* ws = (char*)d_ws;
  unsigned short* H0 = (unsigned short*)ws; ws += (size_t)N_NODES * 128 * 2; // 25.6 MB
  unsigned short* H1 = (unsigned short*)ws; ws += (size_t)N_NODES * 256 * 2; // 51.2 MB
  unsigned short* H2 = (unsigned short*)ws; ws += (size_t)N_NODES * 256 * 2; // 51.2 MB
  unsigned short* HN = (unsigned short*)ws; ws += (size_t)N_NODES * 256 * 2; // 51.2 MB
  int* count  = (int*)ws;  ws += (size_t)(N_NODES + 32) * 4;
  int* startp = (int*)ws;  ws += (size_t)(N_NODES + 32) * 4;
  int* cursor = (int*)ws;  ws += (size_t)(N_NODES + 32) * 4;
  int* esrc   = (int*)ws;  ws += (size_t)N_EDGES * 4;                        // 6.4 MB
  float* invdeg = (float*)ws; ws += (size_t)(N_NODES + 32) * 4;
  int* bsum = (int*)ws;    ws += (size_t)(NB_SCAN + 32) * 4;
  int* boff = (int*)ws;    ws += (size_t)(NB_SCAN + 32) * 4;
  unsigned short* Wb1 = (unsigned short*)ws; ws += 256 * 256 * 2;
  unsigned short* Wb2 = (unsigned short*)ws; ws += 256 * 512 * 2;
  unsigned short* Wb3 = (unsigned short*)ws; ws += 64 * 512 * 2;

  // CSR build (shared across all 3 layers)
  hipMemsetAsync(count, 0, (size_t)N_NODES * 4, stream);
  hist_kernel<<<(N_EDGES + 255) / 256, 256, 0, stream>>>(dst, count);
  scan1_kernel<<<NB_SCAN, 256, 0, stream>>>(count, bsum);
  scan2_kernel<<<1, 512, 0, stream>>>(bsum, boff, startp);
  scan3_kernel<<<NB_SCAN, 256, 0, stream>>>(count, boff, startp, cursor, invdeg);
  fill_kernel<<<(N_EDGES + 255) / 256, 256, 0, stream>>>(src, dst, cursor, esrc);

  // conversions to bf16
  cvt_f32_bf16<<<(N_NODES * 128 / 4 + 255) / 256, 256, 0, stream>>>(x, H0, N_NODES * 128 / 4);
  cvt_f32_bf16<<<(256 * 256 / 4 + 255) / 256, 256, 0, stream>>>(W1, Wb1, 256 * 256 / 4);
  cvt_f32_bf16<<<(256 * 512 / 4 + 255) / 256, 256, 0, stream>>>(W2, Wb2, 256 * 512 / 4);
  cvt_f32_bf16<<<(64 * 512 / 4 + 255) / 256, 256, 0, stream>>>(W3, Wb3, 64 * 512 / 4);

  const int GGRID = (N_NODES * 64 + 255) / 256;    // gather: one wave per node
  const int MG128 = (N_NODES + 127) / 128;         // GEMM grid, BM=128
  const int MG256 = (N_NODES + 255) / 256;         // GEMM grid, BM=256

  // ---- layer 1: D=128 -> 256, relu ----
  gather_mean<128><<<GGRID, 256, 0, stream>>>(H0, startp, esrc, invdeg, HN);
  sage_gemm<128, 256, 128, 128, 64, true, false><<<MG128, 256, 0, stream>>>(H0, HN, Wb1, b1, H1);

  // ---- layer 2: D=256 -> 256, relu ----
  gather_mean<256><<<GGRID, 256, 0, stream>>>(H1, startp, esrc, invdeg, HN);
  sage_gemm<256, 256, 128, 128, 64, true, false><<<MG128, 256, 0, stream>>>(H1, HN, Wb2, b2, H2);

  // ---- layer 3: D=256 -> 64, no relu, fp32 out ----
  gather_mean<256><<<GGRID, 256, 0, stream>>>(H2, startp, esrc, invdeg, HN);
  sage_gemm<256, 64, 256, 64, 64, false, true><<<MG256, 256, 0, stream>>>(H2, HN, Wb3, b3, (float*)d_out);
}

// Round 5
// 765.107 us; speedup vs baseline: 72.8617x; 1.1169x over previous
//
#include <hip/hip_runtime.h>
#include <hip/hip_bf16.h>
#include <cstdint>
#include <cstddef>

#define N_NODES 100000
#define N_EDGES 1600000
#define NB_SCAN ((N_NODES + 255) / 256)   // 391

typedef __attribute__((ext_vector_type(8))) short short8;
typedef __attribute__((ext_vector_type(4))) float floatx4;

__device__ inline float bf_lo(unsigned int u) { return __uint_as_float(u << 16); }
__device__ inline float bf_hi(unsigned int u) { return __uint_as_float(u & 0xffff0000u); }
__device__ inline unsigned short f2bf(float f) {
  unsigned int u = __float_as_uint(f);
  u += 0x7fffu + ((u >> 16) & 1u);   // round-nearest-even
  return (unsigned short)(u >> 16);
}

// ---------- fp32 -> bf16 conversion, 4 elems/thread ----------
__global__ void cvt_f32_bf16(const float* __restrict__ in,
                             unsigned short* __restrict__ out, int n4) {
  int t = blockIdx.x * blockDim.x + threadIdx.x;
  if (t >= n4) return;
  float4 v = ((const float4*)in)[t];
  ushort4 o;
  o.x = f2bf(v.x); o.y = f2bf(v.y); o.z = f2bf(v.z); o.w = f2bf(v.w);
  ((ushort4*)out)[t] = o;
}

// ---------- CSR build: histogram -> hierarchical scan -> fill ----------
__global__ void hist_kernel(const int* __restrict__ dst, int* __restrict__ count) {
  int e = blockIdx.x * blockDim.x + threadIdx.x;
  if (e < N_EDGES) atomicAdd(count + dst[e], 1);
}

__device__ inline int wave_incl_scan(int v, int lane) {
#pragma unroll
  for (int off = 1; off < 64; off <<= 1) {
    int t = __shfl_up(v, off, 64);
    if (lane >= off) v += t;
  }
  return v;
}

// stage 1: per-block sums of count[]
__global__ __launch_bounds__(256)
void scan1_kernel(const int* __restrict__ count, int* __restrict__ bsum) {
  __shared__ int lds[4];
  int i = blockIdx.x * 256 + threadIdx.x;
  int v = (i < N_NODES) ? count[i] : 0;
  int lane = threadIdx.x & 63, wid = threadIdx.x >> 6;
#pragma unroll
  for (int off = 32; off; off >>= 1) v += __shfl_down(v, off, 64);
  if (lane == 0) lds[wid] = v;
  __syncthreads();
  if (threadIdx.x == 0) bsum[blockIdx.x] = lds[0] + lds[1] + lds[2] + lds[3];
}

// stage 2: exclusive scan of the 391 block sums (one block)
__global__ __launch_bounds__(512)
void scan2_kernel(const int* __restrict__ bsum, int* __restrict__ boff,
                  int* __restrict__ start) {
  __shared__ int lds[8];
  int t = threadIdx.x, lane = t & 63, wid = t >> 6;
  int v = (t < NB_SCAN) ? bsum[t] : 0;
  int incl = wave_incl_scan(v, lane);
  if (lane == 63) lds[wid] = incl;
  __syncthreads();
  int woff = 0;
  for (int i = 0; i < wid; ++i) woff += lds[i];
  if (t < NB_SCAN) boff[t] = woff + incl - v;
  if (t == 0) start[N_NODES] = N_EDGES;
}

// stage 3: intra-block exclusive scan + global offset -> start/cursor/invdeg
__global__ __launch_bounds__(256)
void scan3_kernel(const int* __restrict__ count, const int* __restrict__ boff,
                  int* __restrict__ start, int* __restrict__ cursor,
                  float* __restrict__ invdeg) {
  __shared__ int lds[4];
  int i = blockIdx.x * 256 + threadIdx.x;
  int v = (i < N_NODES) ? count[i] : 0;
  int lane = threadIdx.x & 63, wid = threadIdx.x >> 6;
  int incl = wave_incl_scan(v, lane);
  if (lane == 63) lds[wid] = incl;
  __syncthreads();
  int woff = 0;
  for (int w = 0; w < wid; ++w) woff += lds[w];
  if (i < N_NODES) {
    int s = boff[blockIdx.x] + woff + incl - v;
    start[i] = s; cursor[i] = s;
    invdeg[i] = 1.0f / fmaxf((float)v, 1.0f);
  }
}

__global__ void fill_kernel(const int* __restrict__ src, const int* __restrict__ dst,
                            int* __restrict__ cursor, int* __restrict__ esrc) {
  int e = blockIdx.x * blockDim.x + threadIdx.x;
  if (e < N_EDGES) {
    int pos = atomicAdd(cursor + dst[e], 1);
    esrc[pos] = src[e];
  }
}

// ---------- gather-mean: hn[n] = mean over incoming edges of h[src] ----------
template<int D>
__global__ __launch_bounds__(256)
void gather_mean(const unsigned short* __restrict__ h,
                 const int* __restrict__ start,
                 const int* __restrict__ esrc,
                 const float* __restrict__ invdeg,
                 unsigned short* __restrict__ hn) {
  int wave = (int)((blockIdx.x * 256 + threadIdx.x) >> 6);
  if (wave >= N_NODES) return;
  int lane = threadIdx.x & 63;
  int s0 = start[wave], s1 = start[wave + 1];
  constexpr int FPL = D / 64;           // 2 (D=128) or 4 (D=256)
  float acc[FPL] = {};
  const unsigned short* base = h + lane * FPL;

  int e = s0;
  if constexpr (FPL == 4) {
    for (; e + 4 <= s1; e += 4) {
      int sn0 = esrc[e], sn1 = esrc[e + 1], sn2 = esrc[e + 2], sn3 = esrc[e + 3];
      uint2 p0 = *(const uint2*)(base + (size_t)sn0 * D);
      uint2 p1 = *(const uint2*)(base + (size_t)sn1 * D);
      uint2 p2 = *(const uint2*)(base + (size_t)sn2 * D);
      uint2 p3 = *(const uint2*)(base + (size_t)sn3 * D);
      acc[0] += bf_lo(p0.x) + bf_lo(p1.x) + bf_lo(p2.x) + bf_lo(p3.x);
      acc[1] += bf_hi(p0.x) + bf_hi(p1.x) + bf_hi(p2.x) + bf_hi(p3.x);
      acc[2] += bf_lo(p0.y) + bf_lo(p1.y) + bf_lo(p2.y) + bf_lo(p3.y);
      acc[3] += bf_hi(p0.y) + bf_hi(p1.y) + bf_hi(p2.y) + bf_hi(p3.y);
    }
    for (; e < s1; ++e) {
      int sn = esrc[e];
      uint2 p = *(const uint2*)(base + (size_t)sn * D);
      acc[0] += bf_lo(p.x); acc[1] += bf_hi(p.x);
      acc[2] += bf_lo(p.y); acc[3] += bf_hi(p.y);
    }
  } else {
    for (; e + 4 <= s1; e += 4) {
      int sn0 = esrc[e], sn1 = esrc[e + 1], sn2 = esrc[e + 2], sn3 = esrc[e + 3];
      unsigned int p0 = *(const unsigned int*)(base + (size_t)sn0 * D);
      unsigned int p1 = *(const unsigned int*)(base + (size_t)sn1 * D);
      unsigned int p2 = *(const unsigned int*)(base + (size_t)sn2 * D);
      unsigned int p3 = *(const unsigned int*)(base + (size_t)sn3 * D);
      acc[0] += bf_lo(p0) + bf_lo(p1) + bf_lo(p2) + bf_lo(p3);
      acc[1] += bf_hi(p0) + bf_hi(p1) + bf_hi(p2) + bf_hi(p3);
    }
    for (; e < s1; ++e) {
      int sn = esrc[e];
      unsigned int p = *(const unsigned int*)(base + (size_t)sn * D);
      acc[0] += bf_lo(p); acc[1] += bf_hi(p);
    }
  }

  float inv = invdeg[wave];
  unsigned short* out = hn + (size_t)wave * D + lane * FPL;
  if constexpr (FPL == 4) {
    ushort4 o;
    o.x = f2bf(acc[0] * inv); o.y = f2bf(acc[1] * inv);
    o.z = f2bf(acc[2] * inv); o.w = f2bf(acc[3] * inv);
    *(ushort4*)out = o;
  } else {
    ushort2 o;
    o.x = f2bf(acc[0] * inv); o.y = f2bf(acc[1] * inv);
    *(ushort2*)out = o;
  }
}

// ---------- LDS double-buffered fused GEMM (concat + bias [+relu]) ----------
// Block = 4 waves, tile BM=128 x BN (BN = DOUT column-group via blockIdx.y).
// Wave tile 64 x (BN/2): acc NMF x NJF = 4 x (BN/32) frags -> 64 AGPR max,
// keeping VGPR+AGPR ~154 => 3 waves/SIMD, 3 blocks/CU (R4 was 1 wave/SIMD).
// KC=32 chunks staged via global_load_lds(16B) into two separate LDS arrays;
// loads for chunk c+1 issue BEFORE compute on chunk c (flight time ~1 compute
// phase before the barrier's vmcnt drain; 3 blocks/CU cover the rest).
template<int D, int DOUT, int BN, bool RELU, bool OUTF32>
__global__ __launch_bounds__(256)
void sage_gemm(const unsigned short* __restrict__ H,   // N x D bf16 (self)
               const unsigned short* __restrict__ HN,  // N x D bf16 (neigh mean)
               const unsigned short* __restrict__ Wb,  // DOUT x 2D bf16 row-major
               const float* __restrict__ bias,         // DOUT fp32
               void* __restrict__ outp) {              // N x DOUT
  constexpr int K   = 2 * D;
  constexpr int BM  = 128, KC = 32;
  constexpr int NCHUNK = K / KC;          // 8 (D=128) or 16 (D=256), even
  constexpr int AF  = BM / 16;            // 8 A frags per chunk
  constexpr int BF  = BN / 16;            // B frags per chunk
  constexpr int FR  = AF + BF;
  constexpr int NMF = 4;                  // 64 rows per wave
  constexpr int NJF = BF / 2;             // wave covers BN/2 cols

  __shared__ __align__(16) unsigned short lds0[FR * 512];
  __shared__ __align__(16) unsigned short lds1[FR * 512];

  const int tid  = threadIdx.x;
  const int wave = tid >> 6, lane = tid & 63;
  const int l16  = lane & 15, quad = lane >> 4;
  const int n0   = blockIdx.x * BM;
  const int bn0  = blockIdx.y * BN;
  const int wm   = wave >> 1, wn = wave & 1;

  floatx4 acc[NMF][NJF] = {};

  auto stage = [&](int c, unsigned short* buf) {
    const int kc = c * KC;
    const unsigned short* srcH = (kc < D) ? H : HN;
    const int kb = (kc < D) ? kc : kc - D;
    const int w0 = __builtin_amdgcn_readfirstlane(wave);  // scalar LDS base
#pragma unroll
    for (int i = 0; i < FR / 4; ++i) {
      const int fu = w0 + 4 * i;          // wave-uniform scalar frag id
      const unsigned short* g;
      if (fu < AF) {                       // A frag
        int row = min(n0 + fu * 16 + l16, N_NODES - 1);
        g = srcH + (size_t)row * D + kb + quad * 8;
      } else {                             // B frag (W rows = output cols)
        int col = bn0 + (fu - AF) * 16 + l16;
        g = Wb + (size_t)col * K + kc + quad * 8;
      }
      __builtin_amdgcn_global_load_lds(
          (const __attribute__((address_space(1))) unsigned int*)g,
          (__attribute__((address_space(3))) unsigned int*)(buf + fu * 512),
          16, 0, 0);
    }
  };

  auto compute = [&](const unsigned short* buf) {
    short8 b[NJF];
#pragma unroll
    for (int jt = 0; jt < NJF; ++jt)
      b[jt] = *(const short8*)(buf + (AF + wn * NJF + jt) * 512 + lane * 8);
#pragma unroll
    for (int mi = 0; mi < NMF; ++mi) {
      short8 a = *(const short8*)(buf + (wm * NMF + mi) * 512 + lane * 8);
#pragma unroll
      for (int jt = 0; jt < NJF; ++jt)
        acc[mi][jt] = __builtin_amdgcn_mfma_f32_16x16x32_bf16(a, b[jt], acc[mi][jt], 0, 0, 0);
    }
  };

  stage(0, lds0);
  __syncthreads();
#pragma unroll 1
  for (int c = 0; c < NCHUNK; c += 2) {
    stage(c + 1, lds1);                    // prefetch odd chunk
    compute(lds0);
    __syncthreads();                       // drains vmcnt: lds1 ready, lds0 free
    if (c + 2 < NCHUNK) stage(c + 2, lds0);
    compute(lds1);
    __syncthreads();
  }

  // epilogue: C/D layout col=l16, row=quad*4+r
#pragma unroll
  for (int mi = 0; mi < NMF; ++mi) {
#pragma unroll
    for (int jt = 0; jt < NJF; ++jt) {
      int j = bn0 + wn * (NJF * 16) + jt * 16 + l16;
      float bj = bias[j];
#pragma unroll
      for (int r = 0; r < 4; ++r) {
        int node = n0 + wm * 64 + mi * 16 + quad * 4 + r;
        if (node < N_NODES) {
          float v = acc[mi][jt][r] + bj;
          if (RELU) v = fmaxf(v, 0.0f);
          if (OUTF32) ((float*)outp)[(size_t)node * DOUT + j] = v;
          else ((unsigned short*)outp)[(size_t)node * DOUT + j] = f2bf(v);
        }
      }
    }
  }
}

extern "C" void kernel_launch(void* const* d_in, const int* in_sizes, int n_in,
                              void* d_out, int out_size, void* d_ws, size_t ws_size,
                              hipStream_t stream) {
  const float* x   = (const float*)d_in[0];
  const int*   src = (const int*)d_in[1];
  const int*   dst = (const int*)d_in[2];
  const float* W1 = (const float*)d_in[3];
  const float* b1 = (const float*)d_in[4];
  const float* W2 = (const float*)d_in[5];
  const float* b2 = (const float*)d_in[6];
  const float* W3 = (const float*)d_in[7];
  const float* b3 = (const float*)d_in[8];

  char* ws = (char*)d_ws;
  unsigned short* H0 = (unsigned short*)ws; ws += (size_t)N_NODES * 128 * 2; // 25.6 MB
  unsigned short* H1 = (unsigned short*)ws; ws += (size_t)N_NODES * 256 * 2; // 51.2 MB
  unsigned short* H2 = (unsigned short*)ws; ws += (size_t)N_NODES * 256 * 2; // 51.2 MB
  unsigned short* HN = (unsigned short*)ws; ws += (size_t)N_NODES * 256 * 2; // 51.2 MB
  int* count  = (int*)ws;  ws += (size_t)(N_NODES + 32) * 4;
  int* startp = (int*)ws;  ws += (size_t)(N_NODES + 32) * 4;
  int* cursor = (int*)ws;  ws += (size_t)(N_NODES + 32) * 4;
  int* esrc   = (int*)ws;  ws += (size_t)N_EDGES * 4;                        // 6.4 MB
  float* invdeg = (float*)ws; ws += (size_t)(N_NODES + 32) * 4;
  int* bsum = (int*)ws;    ws += (size_t)(NB_SCAN + 32) * 4;
  int* boff = (int*)ws;    ws += (size_t)(NB_SCAN + 32) * 4;
  unsigned short* Wb1 = (unsigned short*)ws; ws += 256 * 256 * 2;
  unsigned short* Wb2 = (unsigned short*)ws; ws += 256 * 512 * 2;
  unsigned short* Wb3 = (unsigned short*)ws; ws += 64 * 512 * 2;

  // CSR build (shared across all 3 layers)
  hipMemsetAsync(count, 0, (size_t)N_NODES * 4, stream);
  hist_kernel<<<(N_EDGES + 255) / 256, 256, 0, stream>>>(dst, count);
  scan1_kernel<<<NB_SCAN, 256, 0, stream>>>(count, bsum);
  scan2_kernel<<<1, 512, 0, stream>>>(bsum, boff, startp);
  scan3_kernel<<<NB_SCAN, 256, 0, stream>>>(count, boff, startp, cursor, invdeg);
  fill_kernel<<<(N_EDGES + 255) / 256, 256, 0, stream>>>(src, dst, cursor, esrc);

  // conversions to bf16
  cvt_f32_bf16<<<(N_NODES * 128 / 4 + 255) / 256, 256, 0, stream>>>(x, H0, N_NODES * 128 / 4);
  cvt_f32_bf16<<<(256 * 256 / 4 + 255) / 256, 256, 0, stream>>>(W1, Wb1, 256 * 256 / 4);
  cvt_f32_bf16<<<(256 * 512 / 4 + 255) / 256, 256, 0, stream>>>(W2, Wb2, 256 * 512 / 4);
  cvt_f32_bf16<<<(64 * 512 / 4 + 255) / 256, 256, 0, stream>>>(W3, Wb3, 64 * 512 / 4);

  const int GGRID = (N_NODES * 64 + 255) / 256;    // gather: one wave per node
  const int MG = (N_NODES + 127) / 128;            // 782 M-tiles

  // ---- layer 1: D=128 -> 256, relu ----
  gather_mean<128><<<GGRID, 256, 0, stream>>>(H0, startp, esrc, invdeg, HN);
  sage_gemm<128, 256, 128, true, false><<<dim3(MG, 2), 256, 0, stream>>>(H0, HN, Wb1, b1, H1);

  // ---- layer 2: D=256 -> 256, relu ----
  gather_mean<256><<<GGRID, 256, 0, stream>>>(H1, startp, esrc, invdeg, HN);
  sage_gemm<256, 256, 128, true, false><<<dim3(MG, 2), 256, 0, stream>>>(H1, HN, Wb2, b2, H2);

  // ---- layer 3: D=256 -> 64, no relu, fp32 out ----
  gather_mean<256><<<GGRID, 256, 0, stream>>>(H2, startp, esrc, invdeg, HN);
  sage_gemm<256, 64, 64, false, true><<<dim3(MG, 1), 256, 0, stream>>>(H2, HN, Wb3, b3, (float*)d_out);
}

// Round 6
// 627.969 us; speedup vs baseline: 88.7734x; 1.2184x over previous
//
#include <hip/hip_runtime.h>
#include <hip/hip_bf16.h>
#include <cstdint>
#include <cstddef>

#define N_NODES 100000
#define N_EDGES 1600000
#define NBUCK   64
#define NPB     1563          // nodes per bucket; 64*1563 = 100032 >= N_NODES
#define NB_E    ((N_EDGES + 4095) / 4096)   // 391 blocks, 4096 edges each

typedef __attribute__((ext_vector_type(8))) short short8;
typedef __attribute__((ext_vector_type(4))) float floatx4;

__device__ inline float bf_lo(unsigned int u) { return __uint_as_float(u << 16); }
__device__ inline float bf_hi(unsigned int u) { return __uint_as_float(u & 0xffff0000u); }
__device__ inline unsigned short f2bf(float f) {
  unsigned int u = __float_as_uint(f);
  u += 0x7fffu + ((u >> 16) & 1u);   // round-nearest-even
  return (unsigned short)(u >> 16);
}

// ---------- fp32 -> bf16 conversion, 4 elems/thread ----------
__global__ void cvt_f32_bf16(const float* __restrict__ in,
                             unsigned short* __restrict__ out, int n4) {
  int t = blockIdx.x * blockDim.x + threadIdx.x;
  if (t >= n4) return;
  float4 v = ((const float4*)in)[t];
  ushort4 o;
  o.x = f2bf(v.x); o.y = f2bf(v.y); o.z = f2bf(v.z); o.w = f2bf(v.w);
  ((ushort4*)out)[t] = o;
}

// W3 (64 x 512 fp32) -> Wcat (128 x 256 bf16): rows 0-63 = self cols, 64-127 = neigh cols
__global__ void cvt_w3cat(const float* __restrict__ W3, unsigned short* __restrict__ out) {
  int t = blockIdx.x * blockDim.x + threadIdx.x;      // 128*256/4 = 8192 threads
  if (t >= 128 * 256 / 4) return;
  int idx4 = t * 4;
  int r = idx4 >> 8, c = idx4 & 255;
  float4 v = *(const float4*)(W3 + (size_t)(r & 63) * 512 + (r >> 6) * 256 + c);
  ushort4 o;
  o.x = f2bf(v.x); o.y = f2bf(v.y); o.z = f2bf(v.z); o.w = f2bf(v.w);
  *(ushort4*)(out + (size_t)r * 256 + c) = o;
}

__device__ inline int wave_incl_scan(int v, int lane) {
#pragma unroll
  for (int off = 1; off < 64; off <<= 1) {
    int t = __shfl_up(v, off, 64);
    if (lane >= off) v += t;
  }
  return v;
}

// ---------- CSR build: bucketed counting sort (no device-scope scatter) ----------
// pass1a: global bucket histogram (64 coarse buckets by dst range)
__global__ __launch_bounds__(256)
void pass1a_kernel(const int* __restrict__ dst, int* __restrict__ bucketCount) {
  __shared__ int hist[NBUCK];
  if (threadIdx.x < NBUCK) hist[threadIdx.x] = 0;
  __syncthreads();
#pragma unroll
  for (int i = 0; i < 16; ++i) {
    int e = blockIdx.x * 4096 + i * 256 + threadIdx.x;
    if (e < N_EDGES) atomicAdd(&hist[dst[e] / NPB], 1);
  }
  __syncthreads();
  if (threadIdx.x < NBUCK) atomicAdd(&bucketCount[threadIdx.x], hist[threadIdx.x]);
}

// scanB: exclusive scan of 64 bucket counts (one wave)
__global__ void scanB_kernel(const int* __restrict__ bucketCount,
                             int* __restrict__ bucketBase, int* __restrict__ gCursorB) {
  int t = threadIdx.x;                  // 64 threads
  int v = bucketCount[t];
  int incl = wave_incl_scan(v, t);
  bucketBase[t] = incl - v;
  gCursorB[t] = incl - v;
  if (t == 63) bucketBase[NBUCK] = incl;   // == N_EDGES
}

// pass1b: stage (src,dst) pairs grouped by bucket; per-(block,bucket) runs are
// contiguous (one global cursor claim per block per bucket), so writes L2-merge.
__global__ __launch_bounds__(256)
void pass1b_kernel(const int* __restrict__ src, const int* __restrict__ dst,
                   int* __restrict__ gCursorB, uint2* __restrict__ staging) {
  __shared__ int hist[NBUCK];
  if (threadIdx.x < NBUCK) hist[threadIdx.x] = 0;
  __syncthreads();
#pragma unroll
  for (int i = 0; i < 16; ++i) {
    int e = blockIdx.x * 4096 + i * 256 + threadIdx.x;
    if (e < N_EDGES) atomicAdd(&hist[dst[e] / NPB], 1);
  }
  __syncthreads();
  if (threadIdx.x < NBUCK)
    hist[threadIdx.x] = atomicAdd(&gCursorB[threadIdx.x], hist[threadIdx.x]);
  __syncthreads();
#pragma unroll
  for (int i = 0; i < 16; ++i) {
    int e = blockIdx.x * 4096 + i * 256 + threadIdx.x;
    if (e < N_EDGES) {
      int d = dst[e];
      int pos = atomicAdd(&hist[d / NPB], 1);     // LDS cursor
      staging[pos] = make_uint2((unsigned)src[e], (unsigned)d);
    }
  }
}

// pass2: one block per bucket. LDS per-node histogram -> block scan -> start/invdeg,
// then scatter esrc via LDS cursors. All scattered writes confined to a ~200 KB
// single-XCD L2-resident region.
__global__ __launch_bounds__(1024)
void pass2_kernel(const uint2* __restrict__ staging, const int* __restrict__ bucketBase,
                  int* __restrict__ start, float* __restrict__ invdeg,
                  int* __restrict__ esrc) {
  __shared__ int cnt[2048];
  __shared__ int cur[2048];
  __shared__ int wsum[16];
  const int b = blockIdx.x, tid = threadIdx.x;
  const int lane = tid & 63, wid = tid >> 6;
  const int n0 = b * NPB, n1 = min(n0 + NPB, N_NODES);
  const int nLocal = n1 - n0;
  const int p0 = bucketBase[b], p1 = bucketBase[b + 1];

  for (int i = tid; i < 2048; i += 1024) cnt[i] = 0;
  __syncthreads();
  for (int e = p0 + tid; e < p1; e += 1024)
    atomicAdd(&cnt[staging[e].y - n0], 1);
  __syncthreads();

  // block-level exclusive scan over 2048 slots (2 per thread)
  int c0 = cnt[2 * tid], c1 = cnt[2 * tid + 1];
  int s = c0 + c1;
  int incl = wave_incl_scan(s, lane);
  if (lane == 63) wsum[wid] = incl;
  __syncthreads();
  if (wid == 0) {
    int v = (lane < 16) ? wsum[lane] : 0;
    int i2 = wave_incl_scan(v, lane);
    if (lane < 16) wsum[lane] = i2 - v;   // exclusive
  }
  __syncthreads();
  int excl = wsum[wid] + incl - s;
  cur[2 * tid] = excl;
  cur[2 * tid + 1] = excl + c0;
  if (2 * tid < nLocal) {
    start[n0 + 2 * tid] = p0 + excl;
    invdeg[n0 + 2 * tid] = 1.0f / fmaxf((float)c0, 1.0f);
  }
  if (2 * tid + 1 < nLocal) {
    start[n0 + 2 * tid + 1] = p0 + excl + c0;
    invdeg[n0 + 2 * tid + 1] = 1.0f / fmaxf((float)c1, 1.0f);
  }
  if (b == NBUCK - 1 && tid == 0) start[N_NODES] = N_EDGES;
  __syncthreads();

  for (int e = p0 + tid; e < p1; e += 1024) {
    uint2 pr = staging[e];
    int pos = p0 + atomicAdd(&cur[pr.y - n0], 1);
    esrc[pos] = (int)pr.x;
  }
}

// ---------- gather-mean: hn[n] = mean over incoming edges of h[src] ----------
template<int D>
__global__ __launch_bounds__(256)
void gather_mean(const unsigned short* __restrict__ h,
                 const int* __restrict__ start,
                 const int* __restrict__ esrc,
                 const float* __restrict__ invdeg,
                 unsigned short* __restrict__ hn) {
  int wave = (int)((blockIdx.x * 256 + threadIdx.x) >> 6);
  if (wave >= N_NODES) return;
  int lane = threadIdx.x & 63;
  int s0 = start[wave], s1 = start[wave + 1];
  constexpr int FPL = D / 64;           // 2 (D=128) or 4 (D=256)
  float acc[FPL] = {};
  const unsigned short* base = h + lane * FPL;

  int e = s0;
  if constexpr (FPL == 4) {
    for (; e + 4 <= s1; e += 4) {
      int sn0 = esrc[e], sn1 = esrc[e + 1], sn2 = esrc[e + 2], sn3 = esrc[e + 3];
      uint2 p0 = *(const uint2*)(base + (size_t)sn0 * D);
      uint2 p1 = *(const uint2*)(base + (size_t)sn1 * D);
      uint2 p2 = *(const uint2*)(base + (size_t)sn2 * D);
      uint2 p3 = *(const uint2*)(base + (size_t)sn3 * D);
      acc[0] += bf_lo(p0.x) + bf_lo(p1.x) + bf_lo(p2.x) + bf_lo(p3.x);
      acc[1] += bf_hi(p0.x) + bf_hi(p1.x) + bf_hi(p2.x) + bf_hi(p3.x);
      acc[2] += bf_lo(p0.y) + bf_lo(p1.y) + bf_lo(p2.y) + bf_lo(p3.y);
      acc[3] += bf_hi(p0.y) + bf_hi(p1.y) + bf_hi(p2.y) + bf_hi(p3.y);
    }
    for (; e < s1; ++e) {
      int sn = esrc[e];
      uint2 p = *(const uint2*)(base + (size_t)sn * D);
      acc[0] += bf_lo(p.x); acc[1] += bf_hi(p.x);
      acc[2] += bf_lo(p.y); acc[3] += bf_hi(p.y);
    }
  } else {
    for (; e + 4 <= s1; e += 4) {
      int sn0 = esrc[e], sn1 = esrc[e + 1], sn2 = esrc[e + 2], sn3 = esrc[e + 3];
      unsigned int p0 = *(const unsigned int*)(base + (size_t)sn0 * D);
      unsigned int p1 = *(const unsigned int*)(base + (size_t)sn1 * D);
      unsigned int p2 = *(const unsigned int*)(base + (size_t)sn2 * D);
      unsigned int p3 = *(const unsigned int*)(base + (size_t)sn3 * D);
      acc[0] += bf_lo(p0) + bf_lo(p1) + bf_lo(p2) + bf_lo(p3);
      acc[1] += bf_hi(p0) + bf_hi(p1) + bf_hi(p2) + bf_hi(p3);
    }
    for (; e < s1; ++e) {
      int sn = esrc[e];
      unsigned int p = *(const unsigned int*)(base + (size_t)sn * D);
      acc[0] += bf_lo(p); acc[1] += bf_hi(p);
    }
  }

  float inv = invdeg[wave];
  unsigned short* out = hn + (size_t)wave * D + lane * FPL;
  if constexpr (FPL == 4) {
    ushort4 o;
    o.x = f2bf(acc[0] * inv); o.y = f2bf(acc[1] * inv);
    o.z = f2bf(acc[2] * inv); o.w = f2bf(acc[3] * inv);
    *(ushort4*)out = o;
  } else {
    ushort2 o;
    o.x = f2bf(acc[0] * inv); o.y = f2bf(acc[1] * inv);
    *(ushort2*)out = o;
  }
}

// ---------- gather_add64: out[n,:] += invdeg * sum of Y3[src,:]  (64 fp32 cols) ----
// Half-wave per edge: lanes 0-31 edge e, lanes 32-63 edge e+1; lane covers 2 feats.
__global__ __launch_bounds__(256)
void gather_add64(const unsigned short* __restrict__ Y3,
                  const int* __restrict__ start, const int* __restrict__ esrc,
                  const float* __restrict__ invdeg, float* __restrict__ out) {
  int wave = (int)((blockIdx.x * 256 + threadIdx.x) >> 6);
  if (wave >= N_NODES) return;
  int lane = threadIdx.x & 63;
  int half = lane >> 5, l32 = lane & 31;
  int s0 = start[wave], s1 = start[wave + 1];
  float a0 = 0.f, a1 = 0.f;
  for (int e = s0 + half; e < s1; e += 2) {
    int sn = esrc[e];
    unsigned int p = *(const unsigned int*)(Y3 + (size_t)sn * 64 + 2 * l32);
    a0 += bf_lo(p); a1 += bf_hi(p);
  }
  a0 += __shfl_xor(a0, 32, 64);
  a1 += __shfl_xor(a1, 32, 64);
  if (half == 0) {
    float inv = invdeg[wave];
    float2* q = (float2*)(out + (size_t)wave * 64 + 2 * l32);
    float2 v = *q;
    v.x += inv * a0; v.y += inv * a1;
    *q = v;
  }
}

// ---------- LDS double-buffered fused GEMM ----------
// MODE 0: out = [H | HN] @ Wb^T + bias (optional relu), K = 2D.
// MODE 1: K = D (reads H only), Wb is 128 x D (rows 0-63 self, 64-127 neigh);
//         cols 0-63 -> d_out fp32 (+bias), cols 64-127 -> Y3 bf16.
template<int D, int DOUT, int BN, bool RELU, bool OUTF32, int MODE>
__global__ __launch_bounds__(256)
void sage_gemm(const unsigned short* __restrict__ H,
               const unsigned short* __restrict__ HN,
               const unsigned short* __restrict__ Wb,
               const float* __restrict__ bias,
               void* __restrict__ outp,
               unsigned short* __restrict__ y3) {
  constexpr int K   = (MODE == 1) ? D : 2 * D;
  constexpr int BM  = 128, KC = 32;
  constexpr int NCHUNK = K / KC;
  constexpr int AF  = BM / 16;
  constexpr int BF  = BN / 16;
  constexpr int FR  = AF + BF;
  constexpr int NMF = 4;
  constexpr int NJF = BF / 2;

  __shared__ __align__(16) unsigned short lds0[FR * 512];
  __shared__ __align__(16) unsigned short lds1[FR * 512];

  const int tid  = threadIdx.x;
  const int wave = tid >> 6, lane = tid & 63;
  const int l16  = lane & 15, quad = lane >> 4;
  const int n0   = blockIdx.x * BM;
  const int bn0  = blockIdx.y * BN;
  const int wm   = wave >> 1, wn = wave & 1;

  floatx4 acc[NMF][NJF] = {};

  auto stage = [&](int c, unsigned short* buf) {
    const int kc = c * KC;
    const unsigned short* srcH = (kc < D) ? H : HN;
    const int kb = (kc < D) ? kc : kc - D;
    const int w0 = __builtin_amdgcn_readfirstlane(wave);
#pragma unroll
    for (int i = 0; i < FR / 4; ++i) {
      const int fu = w0 + 4 * i;
      const unsigned short* g;
      if (fu < AF) {
        int row = min(n0 + fu * 16 + l16, N_NODES - 1);
        g = srcH + (size_t)row * D + kb + quad * 8;
      } else {
        int col = bn0 + (fu - AF) * 16 + l16;
        g = Wb + (size_t)col * K + kc + quad * 8;
      }
      __builtin_amdgcn_global_load_lds(
          (const __attribute__((address_space(1))) unsigned int*)g,
          (__attribute__((address_space(3))) unsigned int*)(buf + fu * 512),
          16, 0, 0);
    }
  };

  auto compute = [&](const unsigned short* buf) {
    short8 b[NJF];
#pragma unroll
    for (int jt = 0; jt < NJF; ++jt)
      b[jt] = *(const short8*)(buf + (AF + wn * NJF + jt) * 512 + lane * 8);
#pragma unroll
    for (int mi = 0; mi < NMF; ++mi) {
      short8 a = *(const short8*)(buf + (wm * NMF + mi) * 512 + lane * 8);
#pragma unroll
      for (int jt = 0; jt < NJF; ++jt)
        acc[mi][jt] = __builtin_amdgcn_mfma_f32_16x16x32_bf16(a, b[jt], acc[mi][jt], 0, 0, 0);
    }
  };

  stage(0, lds0);
  __syncthreads();
#pragma unroll 1
  for (int c = 0; c < NCHUNK; c += 2) {
    stage(c + 1, lds1);
    compute(lds0);
    __syncthreads();
    if (c + 2 < NCHUNK) stage(c + 2, lds0);
    compute(lds1);
    __syncthreads();
  }

#pragma unroll
  for (int mi = 0; mi < NMF; ++mi) {
#pragma unroll
    for (int jt = 0; jt < NJF; ++jt) {
      int j = bn0 + wn * (NJF * 16) + jt * 16 + l16;
      float bj = (MODE == 1 && wn == 1) ? 0.0f : bias[j];
#pragma unroll
      for (int r = 0; r < 4; ++r) {
        int node = n0 + wm * 64 + mi * 16 + quad * 4 + r;
        if (node < N_NODES) {
          float v = acc[mi][jt][r];
          if constexpr (MODE == 1) {
            if (wn == 0) ((float*)outp)[(size_t)node * 64 + j] = v + bj;
            else y3[(size_t)node * 64 + (j - 64)] = f2bf(v);
          } else {
            v += bj;
            if (RELU) v = fmaxf(v, 0.0f);
            if (OUTF32) ((float*)outp)[(size_t)node * DOUT + j] = v;
            else ((unsigned short*)outp)[(size_t)node * DOUT + j] = f2bf(v);
          }
        }
      }
    }
  }
}

extern "C" void kernel_launch(void* const* d_in, const int* in_sizes, int n_in,
                              void* d_out, int out_size, void* d_ws, size_t ws_size,
                              hipStream_t stream) {
  const float* x   = (const float*)d_in[0];
  const int*   src = (const int*)d_in[1];
  const int*   dst = (const int*)d_in[2];
  const float* W1 = (const float*)d_in[3];
  const float* b1 = (const float*)d_in[4];
  const float* W2 = (const float*)d_in[5];
  const float* b2 = (const float*)d_in[6];
  const float* W3 = (const float*)d_in[7];
  const float* b3 = (const float*)d_in[8];

  char* ws = (char*)d_ws;
  unsigned short* H0 = (unsigned short*)ws; ws += (size_t)N_NODES * 128 * 2; // 25.6 MB
  unsigned short* H1 = (unsigned short*)ws; ws += (size_t)N_NODES * 256 * 2; // 51.2 MB
  unsigned short* H2 = (unsigned short*)ws; ws += (size_t)N_NODES * 256 * 2; // 51.2 MB
  unsigned short* HN = (unsigned short*)ws; ws += (size_t)N_NODES * 256 * 2; // 51.2 MB
  uint2* staging = (uint2*)ws; ws += (size_t)N_EDGES * 8;                    // 12.8 MB
  int* esrc   = (int*)ws;  ws += (size_t)N_EDGES * 4;                        // 6.4 MB
  int* startp = (int*)ws;  ws += (size_t)(N_NODES + 32) * 4;
  float* invdeg = (float*)ws; ws += (size_t)(N_NODES + 32) * 4;
  int* bucketCount = (int*)ws; ws += 256;
  int* bucketBase  = (int*)ws; ws += 512;
  int* gCursorB    = (int*)ws; ws += 256;
  unsigned short* Y3 = (unsigned short*)ws; ws += (size_t)N_NODES * 64 * 2;  // 12.8 MB
  unsigned short* Wb1 = (unsigned short*)ws; ws += 256 * 256 * 2;
  unsigned short* Wb2 = (unsigned short*)ws; ws += 256 * 512 * 2;
  unsigned short* Wb3 = (unsigned short*)ws; ws += 128 * 256 * 2;

  // CSR build: bucketed counting sort (shared by all 3 layers)
  hipMemsetAsync(bucketCount, 0, NBUCK * 4, stream);
  pass1a_kernel<<<NB_E, 256, 0, stream>>>(dst, bucketCount);
  scanB_kernel<<<1, 64, 0, stream>>>(bucketCount, bucketBase, gCursorB);
  pass1b_kernel<<<NB_E, 256, 0, stream>>>(src, dst, gCursorB, staging);
  pass2_kernel<<<NBUCK, 1024, 0, stream>>>(staging, bucketBase, startp, invdeg, esrc);

  // conversions to bf16
  cvt_f32_bf16<<<(N_NODES * 128 / 4 + 255) / 256, 256, 0, stream>>>(x, H0, N_NODES * 128 / 4);
  cvt_f32_bf16<<<(256 * 256 / 4 + 255) / 256, 256, 0, stream>>>(W1, Wb1, 256 * 256 / 4);
  cvt_f32_bf16<<<(256 * 512 / 4 + 255) / 256, 256, 0, stream>>>(W2, Wb2, 256 * 512 / 4);
  cvt_w3cat<<<(128 * 256 / 4 + 255) / 256, 256, 0, stream>>>(W3, Wb3);

  const int GGRID = (N_NODES * 64 + 255) / 256;    // one wave per node
  const int MG = (N_NODES + 127) / 128;            // 782 M-tiles

  // ---- layer 1: D=128 -> 256, relu ----
  gather_mean<128><<<GGRID, 256, 0, stream>>>(H0, startp, esrc, invdeg, HN);
  sage_gemm<128, 256, 128, true, false, 0><<<dim3(MG, 2), 256, 0, stream>>>(H0, HN, Wb1, b1, H1, nullptr);

  // ---- layer 2: D=256 -> 256, relu ----
  gather_mean<256><<<GGRID, 256, 0, stream>>>(H1, startp, esrc, invdeg, HN);
  sage_gemm<256, 256, 128, true, false, 0><<<dim3(MG, 2), 256, 0, stream>>>(H1, HN, Wb2, b2, H2, nullptr);

  // ---- layer 3 (aggregate after GEMM): dual GEMM then edge-mean on 64 cols ----
  sage_gemm<256, 128, 128, false, true, 1><<<dim3(MG, 1), 256, 0, stream>>>(H2, nullptr, Wb3, b3, (float*)d_out, Y3);
  gather_add64<<<GGRID, 256, 0, stream>>>(Y3, startp, esrc, invdeg, (float*)d_out);
}